// Round 1
// 67.906 us; speedup vs baseline: 1.1443x; 1.1443x over previous
//
#include <hip/hip_runtime.h>
#include <math.h>

#define HH 224
#define WW 224
#define NS 381                   // splats per image
#define BB 16                    // batch
#define TPB 256                  // 4 waves/block
#define TILE_W 32
#define TILE_H 32
#define TILES_X (WW / TILE_W)    // 7
#define BLKS_PER_IMG (TILES_X * (HH / TILE_H))  // 49
#define NBLK (BB * BLKS_PER_IMG)                // 784
#define NS_PAD 384
#define CUT 19.93f               // exp2 cutoff: weight < 2^-19.93 ~ 1e-6
#define CH 32                    // splat chunk = one K=32 MFMA step
#define EY_STRIDE 33             // f32, +1 pad -> conflict-free gather
#define EXT_STRIDE 40            // halves: 80B rows, 16B-aligned, 2-way on b128 (free)
#define MT_STRIDE 40             // halves
#define OUT_STRIDE 97            // f32

typedef _Float16 f16x8 __attribute__((ext_vector_type(8)));
typedef _Float16 f16x2 __attribute__((ext_vector_type(2)));
typedef float    f32x4 __attribute__((ext_vector_type(4)));

// Separable-Gaussian MFMA formulation, per 32x32 tile:
//   out[c][q] = sum_n ExT[c][n] * MT_t[n][q],  q = 3*r + ch
//   ExT[c][n] = exp2(-(gx_c*ss - px*ss)^2)            (A operand, 32 x m)
//   MT[q][n]  = exp2(-(gy_r*ss - py*ss)^2) * C[n][ch] (B operand stored q-major)
// exp2 evals per (tile,splat): 64 instead of 1024; accumulation on matrix pipe.
union SharedU {
    struct {
        float    ey[CH * EY_STRIDE];          // 4224 B  Ey[n][r]
        _Float16 ext[TILE_W * EXT_STRIDE];    // 2560 B  ExT[c][n] halves
        _Float16 mt[96 * MT_STRIDE];          // 7680 B  MT[q][n] halves
    } s;
    float outb[TILE_W * OUT_STRIDE];          // 12416 B epilogue staging (aliased)
};

__global__ __launch_bounds__(TPB) void splat_render(const float* __restrict__ pos,
                                                    const float* __restrict__ col,
                                                    const float* __restrict__ siz,
                                                    float* __restrict__ out) {
    __shared__ float4 geo[NS_PAD];
    __shared__ int cnt;
    __shared__ SharedU u;

    int blk = blockIdx.x;
    int b = blk / BLKS_PER_IMG;
    int t = blk - b * BLKS_PER_IMG;
    int tile_y = t / TILES_X;
    int tile_x = t - tile_y * TILES_X;

    if (threadIdx.x == 0) cnt = 0;
    __syncthreads();

    const float gstep = 2.0f / (float)(WW - 1);
    float x0 = -1.0f + (float)(tile_x * TILE_W) * gstep;
    float x1 = x0 + (float)(TILE_W - 1) * gstep;
    float y0 = -1.0f + (float)(tile_y * TILE_H) * gstep;
    float y1 = y0 + (float)(TILE_H - 1) * gstep;

    const float2* pb = (const float2*)(pos + (size_t)b * NS * 2);
    const float*  cb = col + (size_t)b * NS * 3;
    const float*  sb = siz + (size_t)b * NS;
    int lane = threadIdx.x & 63;
    int wave = threadIdx.x >> 6;

    // ---- cull + compact into LDS: record = {ss, -px*ss, -py*ss, rgb 10:10:10} ----
    for (int r = 0; r < 2; ++r) {
        int i = threadIdx.x + r * TPB;
        bool pass = false;
        float4 A = make_float4(0.f, 0.f, 0.f, 0.f);
        if (i < NS) {
            float2 p = pb[i];
            float sg = sb[i] * (2.0f / (float)HH);
            float itv = 1.0f / (2.0f * sg * sg + 1e-8f);
            float ss = sqrtf(itv * 1.44269504088896340736f);
            float u_ = p.x * ss, v_ = p.y * ss;
            float dxm = fmaxf(fmaxf(x0 * ss - u_, u_ - x1 * ss), 0.0f);
            float dym = fmaxf(fmaxf(y0 * ss - v_, v_ - y1 * ss), 0.0f);
            pass = fmaf(dxm, dxm, dym * dym) < CUT;
            if (pass) {
                unsigned pr = (unsigned)fmaf(cb[3 * i + 0], 1023.0f, 0.5f);
                unsigned pg = (unsigned)fmaf(cb[3 * i + 1], 1023.0f, 0.5f);
                unsigned pc = (unsigned)fmaf(cb[3 * i + 2], 1023.0f, 0.5f);
                A = make_float4(ss, -u_, -v_, __uint_as_float(pr | (pg << 10) | (pc << 20)));
            }
        }
        unsigned long long mask = __ballot(pass);
        int ofs = __popcll(mask & ((1ull << lane) - 1ull));
        int tot = __popcll(mask);
        int base = 0;
        if (lane == 0 && tot) base = atomicAdd(&cnt, tot);
        base = __shfl(base, 0);
        if (pass) geo[base + ofs] = A;
    }
    __syncthreads();
    int m = cnt;
    int m_pad = (m + (CH - 1)) & ~(CH - 1);
    // zero-pad: ss=0,u=0,v=0 -> Ey=Ex=1 but color=0 -> M=0 -> zero contribution
    for (int i = m + threadIdx.x; i < m_pad; i += TPB)
        geo[i] = make_float4(0.f, 0.f, 0.f, 0.f);
    __syncthreads();

    // wave -> output sub-block: ct = c-halftile (rows of D), qbase = q offset
    int ct = wave & 1;
    int qbase = (wave >> 1) * 48;
    f32x4 acc0 = {0.f, 0.f, 0.f, 0.f};
    f32x4 acc1 = {0.f, 0.f, 0.f, 0.f};
    f32x4 acc2 = {0.f, 0.f, 0.f, 0.f};

    int p2  = threadIdx.x & 15;          // splat-pair id (phase 2)
    int rEy = threadIdx.x & 31;          // row id (phase 1)
    float gyr = y0 + (float)rEy * gstep;

    for (int nb = 0; nb < m_pad; nb += CH) {
        // ---- phase 1: Ey[n][r] = exp2(-(gy*ss - py*ss)^2), 4 items/thread ----
#pragma unroll
        for (int k = 0; k < 4; ++k) {
            int n = (threadIdx.x >> 5) + 8 * k;
            float4 A = geo[nb + n];
            float dy = fmaf(gyr, A.x, A.z);
            u.s.ey[n * EY_STRIDE + rEy] = __builtin_amdgcn_exp2f(-dy * dy);
        }
        __syncthreads();
        // ---- phase 2: ExT (2 items) + MT (6 items); thread owns splat pair 2*p2 ----
        float4 A0 = geo[nb + 2 * p2];
        float4 A1 = geo[nb + 2 * p2 + 1];
#pragma unroll
        for (int k = 0; k < 2; ++k) {
            int c = (threadIdx.x >> 4) + 16 * k;
            float gxc = x0 + (float)c * gstep;
            float dx0 = fmaf(gxc, A0.x, A0.y);
            float dx1 = fmaf(gxc, A1.x, A1.y);
            f16x2 h;
            h.x = (_Float16)__builtin_amdgcn_exp2f(-dx0 * dx0);
            h.y = (_Float16)__builtin_amdgcn_exp2f(-dx1 * dx1);
            *(f16x2*)&u.s.ext[c * EXT_STRIDE + 2 * p2] = h;
        }
        unsigned pk0 = __float_as_uint(A0.w), pk1 = __float_as_uint(A1.w);
#pragma unroll
        for (int k = 0; k < 6; ++k) {
            int q = (threadIdx.x >> 4) + 16 * k;
            int r = (q * 21846) >> 16;       // q/3 for q<96
            int chn = q - 3 * r;
            float cf0 = (float)((pk0 >> (10 * chn)) & 1023u) * (1.0f / 1023.0f);
            float cf1 = (float)((pk1 >> (10 * chn)) & 1023u) * (1.0f / 1023.0f);
            f16x2 h;
            h.x = (_Float16)(u.s.ey[(2 * p2) * EY_STRIDE + r] * cf0);
            h.y = (_Float16)(u.s.ey[(2 * p2 + 1) * EY_STRIDE + r] * cf1);
            *(f16x2*)&u.s.mt[q * MT_STRIDE + 2 * p2] = h;
        }
        __syncthreads();
        // ---- phase 3: one K=32 MFMA step; wave does its 16x48 D block ----
        {
            int koff = (lane >> 4) * 8;
            f16x8 a  = *(const f16x8*)&u.s.ext[((lane & 15) + 16 * ct) * EXT_STRIDE + koff];
            f16x8 b0 = *(const f16x8*)&u.s.mt[(qbase +  0 + (lane & 15)) * MT_STRIDE + koff];
            f16x8 b1 = *(const f16x8*)&u.s.mt[(qbase + 16 + (lane & 15)) * MT_STRIDE + koff];
            f16x8 b2 = *(const f16x8*)&u.s.mt[(qbase + 32 + (lane & 15)) * MT_STRIDE + koff];
            acc0 = __builtin_amdgcn_mfma_f32_16x16x32_f16(a, b0, acc0, 0, 0, 0);
            acc1 = __builtin_amdgcn_mfma_f32_16x16x32_f16(a, b1, acc1, 0, 0, 0);
            acc2 = __builtin_amdgcn_mfma_f32_16x16x32_f16(a, b2, acc2, 0, 0, 0);
        }
        __syncthreads();
    }

    // ---- epilogue: D frags -> outb[c][q] (verified m89 layout: col=lane&15, row=(lane>>4)*4+reg) ----
    int drow = ct * 16 + (lane >> 4) * 4;
    int dcol = qbase + (lane & 15);
#pragma unroll
    for (int rr = 0; rr < 4; ++rr) {
        u.outb[(drow + rr) * OUT_STRIDE + dcol +  0] = acc0[rr];
        u.outb[(drow + rr) * OUT_STRIDE + dcol + 16] = acc1[rr];
        u.outb[(drow + rr) * OUT_STRIDE + dcol + 32] = acc2[rr];
    }
    __syncthreads();

    // ---- reorder + clip + coalesced store: 4 px/thread, 3 float4 per thread ----
    int tx = threadIdx.x & 7;
    int ty = threadIdx.x >> 3;
    int w0 = tile_x * TILE_W + tx * 4;
    int h  = tile_y * TILE_H + ty;
    float v[12];
#pragma unroll
    for (int j = 0; j < 4; ++j) {
        int c = tx * 4 + j;
        v[3 * j + 0] = fminf(u.outb[c * OUT_STRIDE + 3 * ty + 0], 1.f);
        v[3 * j + 1] = fminf(u.outb[c * OUT_STRIDE + 3 * ty + 1], 1.f);
        v[3 * j + 2] = fminf(u.outb[c * OUT_STRIDE + 3 * ty + 2], 1.f);
    }
    float4* o4 = (float4*)(out + ((size_t)b * (HH * WW) + (size_t)h * WW + w0) * 3);
    o4[0] = make_float4(v[0], v[1], v[2], v[3]);
    o4[1] = make_float4(v[4], v[5], v[6], v[7]);
    o4[2] = make_float4(v[8], v[9], v[10], v[11]);
}

extern "C" void kernel_launch(void* const* d_in, const int* in_sizes, int n_in,
                              void* d_out, int out_size, void* d_ws, size_t ws_size,
                              hipStream_t stream) {
    const float* pos = (const float*)d_in[0];
    const float* col = (const float*)d_in[1];
    const float* siz = (const float*)d_in[2];
    float* out = (float*)d_out;
    splat_render<<<NBLK, TPB, 0, stream>>>(pos, col, siz, out);
}

// Round 2
// 67.249 us; speedup vs baseline: 1.1555x; 1.0098x over previous
//
#include <hip/hip_runtime.h>
#include <math.h>

#define HH 224
#define WW 224
#define NS 381                   // splats per image
#define BB 16                    // batch
#define TPB 256                  // 4 waves/block
#define TILE_W 32
#define TILE_H 32
#define TILES_X (WW / TILE_W)    // 7
#define BLKS_PER_IMG (TILES_X * (HH / TILE_H))  // 49
#define NBLK (BB * BLKS_PER_IMG)                // 784
#define NS_PAD 384
#define CUT 19.93f               // exp2 cutoff: weight < 2^-19.93 ~ 1e-6
#define CH 32                    // splat chunk = one K=32 MFMA step
#define OUT_STRIDE 97            // f32 epilogue staging stride

typedef _Float16 f16x8 __attribute__((ext_vector_type(8)));
typedef float    f32x4 __attribute__((ext_vector_type(4)));

// Separable-Gaussian MFMA, all-register formulation. Per 32x32 tile:
//   out_ch[c][r] = sum_n (Ex[c][n]*C[n][ch]) * Ey[n][r]
//   A_ch[c][k]   = exp2(-(gx_c*ss_k + u_k)^2) * C[k][ch]   (in-register)
//   B[k][r]      = exp2(-(gy_r*ss_k + v_k)^2)              (in-register)
// Each lane builds its own fragments from broadcast reads of the compacted
// splat records -> ZERO barriers / zero LDS staging in the chunk loop.
// k-mapping (lane>>4)*8+j identical on A and B (consistency is all that's
// required); D layout per m89: N=lane&15 (-> r), M=(lane>>4)*4+reg (-> c).

__global__ __launch_bounds__(TPB) void splat_render(const float* __restrict__ pos,
                                                    const float* __restrict__ col,
                                                    const float* __restrict__ siz,
                                                    float* __restrict__ out) {
    __shared__ float4 geo[NS_PAD];   // {ss, -px*ss, -py*ss, 0}
    __shared__ float4 colg[NS_PAD];  // {r, g, b, 0}
    __shared__ float outb[TILE_W * OUT_STRIDE];
    __shared__ int cnt;

    int blk = blockIdx.x;
    int b = blk / BLKS_PER_IMG;
    int t = blk - b * BLKS_PER_IMG;
    int tile_y = t / TILES_X;
    int tile_x = t - tile_y * TILES_X;

    if (threadIdx.x == 0) cnt = 0;
    __syncthreads();

    const float gstep = 2.0f / (float)(WW - 1);
    float x0 = -1.0f + (float)(tile_x * TILE_W) * gstep;
    float x1 = x0 + (float)(TILE_W - 1) * gstep;
    float y0 = -1.0f + (float)(tile_y * TILE_H) * gstep;
    float y1 = y0 + (float)(TILE_H - 1) * gstep;

    const float2* pb = (const float2*)(pos + (size_t)b * NS * 2);
    const float*  cb = col + (size_t)b * NS * 3;
    const float*  sb = siz + (size_t)b * NS;
    int lane = threadIdx.x & 63;
    int wave = threadIdx.x >> 6;

    // ---- cull + compact into LDS ----
    for (int r = 0; r < 2; ++r) {
        int i = threadIdx.x + r * TPB;
        bool pass = false;
        float4 A = make_float4(0.f, 0.f, 0.f, 0.f);
        float4 Cc = make_float4(0.f, 0.f, 0.f, 0.f);
        if (i < NS) {
            float2 p = pb[i];
            float sg = sb[i] * (2.0f / (float)HH);
            float itv = 1.0f / (2.0f * sg * sg + 1e-8f);
            float ss = sqrtf(itv * 1.44269504088896340736f);
            float u_ = p.x * ss, v_ = p.y * ss;
            float dxm = fmaxf(fmaxf(x0 * ss - u_, u_ - x1 * ss), 0.0f);
            float dym = fmaxf(fmaxf(y0 * ss - v_, v_ - y1 * ss), 0.0f);
            pass = fmaf(dxm, dxm, dym * dym) < CUT;
            if (pass) {
                A = make_float4(ss, -u_, -v_, 0.f);
                Cc = make_float4(cb[3 * i + 0], cb[3 * i + 1], cb[3 * i + 2], 0.f);
            }
        }
        unsigned long long mask = __ballot(pass);
        int ofs = __popcll(mask & ((1ull << lane) - 1ull));
        int tot = __popcll(mask);
        int base = 0;
        if (lane == 0 && tot) base = atomicAdd(&cnt, tot);
        base = __shfl(base, 0);
        if (pass) { geo[base + ofs] = A; colg[base + ofs] = Cc; }
    }
    __syncthreads();
    int m = cnt;
    int m_pad = (m + (CH - 1)) & ~(CH - 1);
    // zero-pad: ss=0,u=0,v=0 -> Ex=Ey=1 but color=0 -> zero contribution
    for (int i = m + threadIdx.x; i < m_pad; i += TPB) {
        geo[i]  = make_float4(0.f, 0.f, 0.f, 0.f);
        colg[i] = make_float4(0.f, 0.f, 0.f, 0.f);
    }
    __syncthreads();
    m_pad = __builtin_amdgcn_readfirstlane(m_pad);

    // wave -> 16x16 D block per channel: ct = c-half, rt = r-half
    int ct = wave & 1;
    int rt = wave >> 1;
    float gxc = x0 + (float)(16 * ct + (lane & 15)) * gstep;  // A row -> column c
    float gyr = y0 + (float)(16 * rt + (lane & 15)) * gstep;  // B col -> row r
    f32x4 acc0 = {0.f, 0.f, 0.f, 0.f};
    f32x4 acc1 = {0.f, 0.f, 0.f, 0.f};
    f32x4 acc2 = {0.f, 0.f, 0.f, 0.f};

    int kg = (lane >> 4) * 8;     // this lane's k-group of 8 splats

    for (int nb = 0; nb < m_pad; nb += CH) {
        f16x8 af0, af1, af2, bf;
#pragma unroll
        for (int j = 0; j < 8; ++j) {
            float4 A  = geo[nb + kg + j];    // broadcast within 16-lane group
            float4 Cc = colg[nb + kg + j];
            float dx = fmaf(gxc, A.x, A.y);
            float ex = __builtin_amdgcn_exp2f(-dx * dx);
            float dy = fmaf(gyr, A.x, A.z);
            bf[j]  = (_Float16)__builtin_amdgcn_exp2f(-dy * dy);
            af0[j] = (_Float16)(ex * Cc.x);
            af1[j] = (_Float16)(ex * Cc.y);
            af2[j] = (_Float16)(ex * Cc.z);
        }
        acc0 = __builtin_amdgcn_mfma_f32_16x16x32_f16(af0, bf, acc0, 0, 0, 0);
        acc1 = __builtin_amdgcn_mfma_f32_16x16x32_f16(af1, bf, acc1, 0, 0, 0);
        acc2 = __builtin_amdgcn_mfma_f32_16x16x32_f16(af2, bf, acc2, 0, 0, 0);
    }

    // ---- epilogue: D frags -> outb[c][3r+ch] (m89: col=lane&15 -> r, row=(lane>>4)*4+reg -> c) ----
    __syncthreads();   // geo/colg no longer needed; outb is fresh
    int rglob = 16 * rt + (lane & 15);
#pragma unroll
    for (int rr = 0; rr < 4; ++rr) {
        int cglob = 16 * ct + (lane >> 4) * 4 + rr;
        outb[cglob * OUT_STRIDE + 3 * rglob + 0] = acc0[rr];
        outb[cglob * OUT_STRIDE + 3 * rglob + 1] = acc1[rr];
        outb[cglob * OUT_STRIDE + 3 * rglob + 2] = acc2[rr];
    }
    __syncthreads();

    // ---- reorder + clip + coalesced store: 4 px/thread, 3 float4 per thread ----
    int tx = threadIdx.x & 7;
    int ty = threadIdx.x >> 3;
    int w0 = tile_x * TILE_W + tx * 4;
    int h  = tile_y * TILE_H + ty;
    float v[12];
#pragma unroll
    for (int j = 0; j < 4; ++j) {
        int c = tx * 4 + j;
        v[3 * j + 0] = fminf(outb[c * OUT_STRIDE + 3 * ty + 0], 1.f);
        v[3 * j + 1] = fminf(outb[c * OUT_STRIDE + 3 * ty + 1], 1.f);
        v[3 * j + 2] = fminf(outb[c * OUT_STRIDE + 3 * ty + 2], 1.f);
    }
    float4* o4 = (float4*)(out + ((size_t)b * (HH * WW) + (size_t)h * WW + w0) * 3);
    o4[0] = make_float4(v[0], v[1], v[2], v[3]);
    o4[1] = make_float4(v[4], v[5], v[6], v[7]);
    o4[2] = make_float4(v[8], v[9], v[10], v[11]);
}

extern "C" void kernel_launch(void* const* d_in, const int* in_sizes, int n_in,
                              void* d_out, int out_size, void* d_ws, size_t ws_size,
                              hipStream_t stream) {
    const float* pos = (const float*)d_in[0];
    const float* col = (const float*)d_in[1];
    const float* siz = (const float*)d_in[2];
    float* out = (float*)d_out;
    splat_render<<<NBLK, TPB, 0, stream>>>(pos, col, siz, out);
}